// Round 2
// baseline (1226.892 us; speedup 1.0000x reference)
//
#include <hip/hip_runtime.h>
#include <hip/hip_bf16.h>
#include <math.h>

#define NDIM 512
#define NB   128
#define NMAT 129
#define EPSF 1e-7f
#define MS  ((size_t)262144)   // matrix stride (floats) = 512*512
#define LTS ((size_t)32768)    // Lt stride per matrix (floats) = 64*512
#define PSTR ((size_t)524288)  // E2 plane stride (floats) = 512*512*2

// workspace layout (float offsets)
#define OFF_E   ((size_t)0)                    // 2 planes * 524288 = 1,048,576
#define OFF_WM  ((size_t)1048576)              // 262,144
#define OFF_V   ((size_t)(OFF_WM + 262144))    // 1,024
#define OFF_IPR ((size_t)(OFF_V + 1024))       // 65,536
#define OFF_LPR ((size_t)(OFF_IPR + 65536))    // 128
#define OFF_LD  ((size_t)(OFF_LPR + 128))      // 129 (pad to 1,377,792)
#define OFF_LT  ((size_t)1377792)              // 129*32768 = 4,227,072
#define OFF_MAT ((size_t)(OFF_LT + (size_t)NMAT*LTS))   // ~158 MB total

// ---------- V = softmax(V_compress, axis=1) ----------
__global__ __launch_bounds__(256) void k_V(const float* __restrict__ Vc, float* __restrict__ V) {
  int i = blockIdx.x * 256 + threadIdx.x;
  if (i < NDIM) {
    float v0 = Vc[2*i], v1 = Vc[2*i+1];
    float mx = fmaxf(v0, v1);
    float e0 = expf(v0 - mx), e1 = expf(v1 - mx);
    float s = e0 + e1;
    V[2*i]   = e0 / s;
    V[2*i+1] = e1 / s;
  }
}

// ---------- Wm = sym(tril(sigmoid(W), -1)) ----------
__global__ __launch_bounds__(256) void k_Wm(const float* __restrict__ W, float* __restrict__ Wm) {
  int idx = blockIdx.x * 256 + threadIdx.x;
  int i = idx >> 9, j = idx & 511;
  float v = 0.f;
  if (i > j)      v = 1.f / (1.f + expf(-W[i*NDIM + j]));
  else if (i < j) v = 1.f / (1.f + expf(-W[j*NDIM + i]));
  Wm[idx] = v;
}

// ---------- per-(i,j) 2x2 IPF on E; output as xi-planes, xj interleaved ----------
// E2[xi][(i*512+j)*2 + xj]
__global__ __launch_bounds__(256) void k_E(const float* __restrict__ Ec, const float* __restrict__ V,
                                           float* __restrict__ E2) {
  int idx = blockIdx.x * 256 + threadIdx.x;   // i*512 + j
  int i = idx >> 9, j = idx & 511;
  float4 ec = reinterpret_cast<const float4*>(Ec)[idx];
  float e00 = expf(ec.x), e01 = expf(ec.y), e10 = expf(ec.z), e11 = expf(ec.w);
  float s = e00 + e01 + e10 + e11;
  float inv = 1.f / s;
  e00 *= inv; e01 *= inv; e10 *= inv; e11 *= inv;
  float A0 = V[2*i], A1 = V[2*i+1];
  float B0 = V[2*j], B1 = V[2*j+1];
  for (int t = 0; t < 10; ++t) {
    float rm0 = e00 + e01 + EPSF, rm1 = e10 + e11 + EPSF;
    float cm0 = e00 + e10 + EPSF, cm1 = e01 + e11 + EPSF;
    float f0 = A0 / rm0, f1 = A1 / rm1;
    e00 *= f0; e01 *= f0; e10 *= f1; e11 *= f1;
    float g0 = B0 / cm0, g1 = B1 / cm1;
    e00 *= g0; e10 *= g0; e01 *= g1; e11 *= g1;
    float ss = e00 + e01 + e10 + e11 + EPSF;
    float iv = 1.f / ss;
    e00 *= iv; e01 *= iv; e10 *= iv; e11 *= iv;
  }
  if (i == j) { e00 = 0.f; e01 = 0.f; e10 = 0.f; e11 = 0.f; }
  e00 = fminf(fmaxf(e00, 0.f), 1.f);
  e01 = fminf(fmaxf(e01, 0.f), 1.f);
  e10 = fminf(fmaxf(e10, 0.f), 1.f);
  e11 = fminf(fmaxf(e11, 0.f), 1.f);
  reinterpret_cast<float2*>(E2)[idx]               = make_float2(e00, e01);  // plane xi=0
  reinterpret_cast<float2*>(E2 + PSTR)[idx]        = make_float2(e10, e11);  // plane xi=1
}

// ---------- Pr, invPr, sum(log Pr) per batch ----------
__global__ __launch_bounds__(256) void k_Pr(const int* __restrict__ x, const float* __restrict__ V,
                                            float* __restrict__ invPr, float* __restrict__ logPr) {
  const int b = blockIdx.x;
  const int tid = threadIdx.x;
  float acc = 0.f;
  for (int ii = tid; ii < NDIM; ii += 256) {
    const int xv = x[b*NDIM + ii];
    const float p = V[2*ii + xv];
    invPr[b*NDIM + ii] = 1.f / p;
    acc += logf(p);
  }
  for (int off = 32; off > 0; off >>= 1) acc += __shfl_down(acc, off, 64);
  __shared__ float sw[4];
  if ((tid & 63) == 0) sw[tid >> 6] = acc;
  __syncthreads();
  if (tid == 0) logPr[b] = sw[0] + sw[1] + sw[2] + sw[3];
}

// ---------- build full 512x512 embedded minors: row0 = e0, col0 = 0 ----------
// det(M) == det(Lb[1:,1:]); wave-per-row, 8 elems/lane, aligned float4 I/O, no barriers
__global__ __launch_bounds__(512) void k_build(const int* __restrict__ x, const float* __restrict__ E2,
                                               const float* __restrict__ Wm, const float* __restrict__ invPr,
                                               float* __restrict__ Mall) {
  const int b = blockIdx.x;                        // 0..128 (fast -> L2 reuse of Wm/E2 rows)
  const int i = blockIdx.y*8 + (threadIdx.x >> 6); // row 0..511, wave-uniform
  const int lane = threadIdx.x & 63;
  const int j0 = lane << 3;                        // 8 consecutive j per lane

  const float4 w0 = *(const float4*)(Wm + (size_t)i*NDIM + j0);
  const float4 w1 = *(const float4*)(Wm + (size_t)i*NDIM + j0 + 4);
  float wp[8];
  if (b < NB) {
    const int   xi   = x[b*NDIM + i];              // wave-uniform
    const float ipri = invPr[b*NDIM + i];          // wave-uniform
    const int4  xa = *(const int4*)(x + b*NDIM + j0);
    const int4  xb = *(const int4*)(x + b*NDIM + j0 + 4);
    const float4 pa = *(const float4*)(invPr + b*NDIM + j0);
    const float4 pb = *(const float4*)(invPr + b*NDIM + j0 + 4);
    // E2 pairs (xj=0,1) adjacent: one contiguous 64B chunk per lane
    const float* pl = E2 + (size_t)xi*PSTR + ((size_t)i*NDIM + j0)*2;
    const float4 ea = *(const float4*)(pl);
    const float4 eb = *(const float4*)(pl + 4);
    const float4 ec = *(const float4*)(pl + 8);
    const float4 ed = *(const float4*)(pl + 12);
    wp[0] = w0.x * (xa.x ? ea.y : ea.x) * pa.x;
    wp[1] = w0.y * (xa.y ? ea.w : ea.z) * pa.y;
    wp[2] = w0.z * (xa.z ? eb.y : eb.x) * pa.z;
    wp[3] = w0.w * (xa.w ? eb.w : eb.z) * pa.w;
    wp[4] = w1.x * (xb.x ? ec.y : ec.x) * pb.x;
    wp[5] = w1.y * (xb.y ? ec.w : ec.z) * pb.y;
    wp[6] = w1.z * (xb.z ? ed.y : ed.x) * pb.z;
    wp[7] = w1.w * (xb.w ? ed.w : ed.z) * pb.w;
    #pragma unroll
    for (int k = 0; k < 8; ++k) wp[k] *= ipri;
  } else {
    wp[0]=w0.x; wp[1]=w0.y; wp[2]=w0.z; wp[3]=w0.w;
    wp[4]=w1.x; wp[5]=w1.y; wp[6]=w1.z; wp[7]=w1.w;
  }
  // full row sum (includes j==0 term, matching reference diag) — in-wave butterfly
  float s = ((wp[0]+wp[1])+(wp[2]+wp[3])) + ((wp[4]+wp[5])+(wp[6]+wp[7]));
  #pragma unroll
  for (int off = 32; off > 0; off >>= 1) s += __shfl_xor(s, off, 64);

  float o[8];
  #pragma unroll
  for (int k = 0; k < 8; ++k) o[k] = -wp[k];
  if (i == 0) {
    #pragma unroll
    for (int k = 0; k < 8; ++k) o[k] = 0.f;
    if (lane == 0) o[0] = 1.f;                    // row 0 = e0
  } else {
    if (lane == 0) o[0] = 0.f;                    // col 0 = 0
    #pragma unroll
    for (int k = 0; k < 8; ++k)                   // static indices only (no scratch)
      if (j0 + k == i) o[k] = s;                  // diagonal = full row sum
  }
  float* dst = Mall + (size_t)b*MS + (size_t)i*NDIM + j0;
  *(float4*)(dst)   = make_float4(o[0],o[1],o[2],o[3]);
  *(float4*)(dst+4) = make_float4(o[4],o[5],o[6],o[7]);
}

// ---------- panel factorization: template-recursive steps, indices all static ----------
template<int KK>
struct PanelStep {
  static __device__ __forceinline__ void run(float (&a)[64], float (*pivrow)[72],
                                             int t, int m, float& logp) {
    float* pb = pivrow[KK & 1];
    if (t == KK) {
      #pragma unroll
      for (int c = 0; c < 16; ++c)
        *(float4*)(pb + c*4) = make_float4(a[c*4], a[c*4+1], a[c*4+2], a[c*4+3]);
      pb[64] = 1.0f / a[KK];          // pivot reciprocal, computed once
      logp += logf(fabsf(a[KK]));
    }
    __syncthreads();
    if (t > KK && t < m) {
      const float l = a[KK] * pb[64];
      a[KK] = l;
      #pragma unroll
      for (int c = KK + 1; c < 64; ++c)
        a[c] -= l * pb[c];
    }
    PanelStep<KK + 1>::run(a, pivrow, t, m, logp);
  }
};
template<>
struct PanelStep<64> {
  static __device__ __forceinline__ void run(float (&)[64], float (*)[72], int, int, float&) {}
};

// ---------- persistent per-matrix LU: all 8 steps of panel+TRSM+trailing GEMM ----------
// one workgroup per matrix; phases separated only by __syncthreads (no launch boundaries)
__global__ __launch_bounds__(512) void k_LU(float* __restrict__ Mall, float* __restrict__ LtAll,
                                            float* __restrict__ logdets) {
  const int b = blockIdx.x;
  float* __restrict__ M = Mall + (size_t)b*MS;
  float* __restrict__ L = LtAll + (size_t)b*LTS;
  const int t = threadIdx.x;
  const int tx = t & 15, ty = t >> 4;          // GEMM mapping: 4 cols x 2 rows per thread
  __shared__ float pivrow[2][72];
  __shared__ float Ls[64][72];                 // Ls[p][kk] = L11(kk,p) for TRSM
  __shared__ float As[64][68];                 // As[p][r]  = L21[r][p]
  __shared__ float Bs[64][68];                 // Bs[p][c]  = U12[p][c]
  float ldall = 0.f;

  for (int s = 0; s < 8; ++s) {
    const int k0 = s*64;
    const int m = NDIM - k0;                   // 512,448,...,64
    const int mrem = m - 64;

    // ---- panel: rows in registers, pivot-row broadcast via LDS ----
    float a[64];
    if (t < m) {
      const float* row = M + (size_t)(k0+t)*NDIM + k0;
      #pragma unroll
      for (int c4 = 0; c4 < 16; ++c4) {
        float4 v = *(const float4*)(row + c4*4);
        a[c4*4+0]=v.x; a[c4*4+1]=v.y; a[c4*4+2]=v.z; a[c4*4+3]=v.w;
      }
    }
    float logp = 0.f;
    PanelStep<0>::run(a, pivrow, t, m, logp);
    // write transposed panel: Lt[c][r]; lanes over r -> coalesced
    if (t < m) {
      #pragma unroll
      for (int c = 0; c < 64; ++c) L[(size_t)c*NDIM + t] = a[c];
    }
    if (t < 64) {
      // thread t = row t of L11; write full row transposed (only kk>p is ever read)
      #pragma unroll
      for (int c = 0; c < 64; ++c) Ls[c][t] = a[c];
      float v = logp;
      for (int off = 32; off > 0; off >>= 1) v += __shfl_down(v, off, 64);
      if (t == 0) ldall += v;
    }
    __syncthreads();

    if (mrem > 0) {
      // ---- TRSM: U12 = L11^{-1} A12, one column per thread (mrem <= 448 < 512) ----
      if (t < mrem) {
        const int col = k0 + 64 + t;
        float u[64];
        #pragma unroll
        for (int r = 0; r < 64; ++r) u[r] = M[(size_t)(k0+r)*NDIM + col];
        #pragma unroll
        for (int p = 0; p < 63; ++p) {
          const float lv = u[p];
          #pragma unroll
          for (int kk = p+1; kk < 64; ++kk)
            u[kk] -= Ls[p][kk] * lv;
        }
        #pragma unroll
        for (int r = 1; r < 64; ++r) M[(size_t)(k0+r)*NDIM + col] = u[r];
      }
      __syncthreads();

      // ---- trailing update: C -= L21 * U12, 64x64 tiles, 512 threads (2x4/thread) ----
      const int nt = mrem >> 6;
      for (int ti = 0; ti < nt; ++ti) {
        const int rowbase = 64 + ti*64;
        for (int tj = 0; tj < nt; ++tj) {
          const int colbase = 64 + tj*64;
          float* Crow = M + (size_t)(k0+rowbase+ty*2)*NDIM + (k0+colbase+tx*4);
          float4 c0 = *(float4*)(Crow);
          float4 c1 = *(float4*)(Crow + NDIM);
          __syncthreads();                 // previous tile's LDS readers done
          #pragma unroll
          for (int i2 = 0; i2 < 2; ++i2) {
            int q = t + 512*i2;            // 1024 float4 per buffer
            int p = q >> 4, f = q & 15;
            *(float4*)&As[p][f*4] = *(const float4*)&L[(size_t)p*NDIM + rowbase + f*4];
            *(float4*)&Bs[p][f*4] = *(const float4*)&M[(size_t)(k0+p)*NDIM + (k0+colbase) + f*4];
          }
          __syncthreads();                 // tiles staged
          #pragma unroll
          for (int p = 0; p < 64; ++p) {
            const float2 av = *(const float2*)&As[p][ty*2];
            const float4 bv = *(const float4*)&Bs[p][tx*4];
            c0.x -= av.x*bv.x; c0.y -= av.x*bv.y; c0.z -= av.x*bv.z; c0.w -= av.x*bv.w;
            c1.x -= av.y*bv.x; c1.y -= av.y*bv.y; c1.z -= av.y*bv.z; c1.w -= av.y*bv.w;
          }
          *(float4*)(Crow)        = c0;
          *(float4*)(Crow + NDIM) = c1;
        }
      }
    }
    __syncthreads();   // C stores drained; Ls/pivrow free for next step
  }
  if (t == 0) logdets[b] = ldall;
}

// ---------- final combine ----------
__global__ void k_final(const float* __restrict__ logPr, const float* __restrict__ logdets,
                        float* __restrict__ out) {
  int t = threadIdx.x;
  if (t < NB) out[t] = logPr[t] + logdets[t] - logdets[NB];
}

extern "C" void kernel_launch(void* const* d_in, const int* in_sizes, int n_in,
                              void* d_out, int out_size, void* d_ws, size_t ws_size,
                              hipStream_t stream) {
  const int*   x  = (const int*)  d_in[0];
  const float* W  = (const float*)d_in[1];
  const float* Vc = (const float*)d_in[2];
  const float* Ec = (const float*)d_in[3];
  float* out = (float*)d_out;
  float* ws  = (float*)d_ws;
  (void)in_sizes; (void)n_in; (void)out_size; (void)ws_size;  // needs ~158 MiB of ws

  float* Mat = ws + OFF_MAT;
  float* Lt  = ws + OFF_LT;
  float* Ld  = ws + OFF_LD;

  k_V  <<<2,    256, 0, stream>>>(Vc, ws + OFF_V);
  k_Wm <<<1024, 256, 0, stream>>>(W,  ws + OFF_WM);
  k_E  <<<1024, 256, 0, stream>>>(Ec, ws + OFF_V, ws + OFF_E);
  k_Pr <<<NB,   256, 0, stream>>>(x,  ws + OFF_V, ws + OFF_IPR, ws + OFF_LPR);
  dim3 gb(NMAT, 64);
  k_build<<<gb, 512, 0, stream>>>(x, ws + OFF_E, ws + OFF_WM, ws + OFF_IPR, Mat);

  k_LU<<<NMAT, 512, 0, stream>>>(Mat, Lt, Ld);

  k_final<<<1, 128, 0, stream>>>(ws + OFF_LPR, Ld, out);
}

// Round 3
// 628.113 us; speedup vs baseline: 1.9533x; 1.9533x over previous
//
#include <hip/hip_runtime.h>
#include <hip/hip_bf16.h>
#include <math.h>

#define NDIM 512
#define NB   128
#define NMAT 129
#define EPSF 1e-7f
#define MS  ((size_t)262144)   // matrix stride (floats) = 512*512
#define LTS ((size_t)32768)    // Lt stride per matrix (floats) = 64*512
#define PSTR ((size_t)524288)  // E2 plane stride (floats) = 512*512*2

// workspace layout (float offsets)
#define OFF_E   ((size_t)0)                    // 2 planes * 524288 = 1,048,576
#define OFF_WM  ((size_t)1048576)              // 262,144
#define OFF_V   ((size_t)(OFF_WM + 262144))    // 1,024
#define OFF_IPR ((size_t)(OFF_V + 1024))       // 65,536
#define OFF_LPR ((size_t)(OFF_IPR + 65536))    // 128
#define OFF_LD  ((size_t)(OFF_LPR + 128))      // 129 (pad to 1,377,792)
#define OFF_LT  ((size_t)1377792)              // 129*32768 = 4,227,072
#define OFF_MAT ((size_t)(OFF_LT + (size_t)NMAT*LTS))   // ~158 MB total

__device__ __forceinline__ float rdlane(float v, int l) {
  return __uint_as_float((unsigned)__builtin_amdgcn_readlane((int)__float_as_uint(v), l));
}

// ---------- V = softmax(V_compress, axis=1) ----------
__global__ __launch_bounds__(256) void k_V(const float* __restrict__ Vc, float* __restrict__ V) {
  int i = blockIdx.x * 256 + threadIdx.x;
  if (i < NDIM) {
    float v0 = Vc[2*i], v1 = Vc[2*i+1];
    float mx = fmaxf(v0, v1);
    float e0 = expf(v0 - mx), e1 = expf(v1 - mx);
    float s = e0 + e1;
    V[2*i]   = e0 / s;
    V[2*i+1] = e1 / s;
  }
}

// ---------- Wm = sym(tril(sigmoid(W), -1)) ----------
__global__ __launch_bounds__(256) void k_Wm(const float* __restrict__ W, float* __restrict__ Wm) {
  int idx = blockIdx.x * 256 + threadIdx.x;
  int i = idx >> 9, j = idx & 511;
  float v = 0.f;
  if (i > j)      v = 1.f / (1.f + expf(-W[i*NDIM + j]));
  else if (i < j) v = 1.f / (1.f + expf(-W[j*NDIM + i]));
  Wm[idx] = v;
}

// ---------- per-(i,j) 2x2 IPF on E; output as xi-planes, xj interleaved ----------
// E2[xi][(i*512+j)*2 + xj]
__global__ __launch_bounds__(256) void k_E(const float* __restrict__ Ec, const float* __restrict__ V,
                                           float* __restrict__ E2) {
  int idx = blockIdx.x * 256 + threadIdx.x;   // i*512 + j
  int i = idx >> 9, j = idx & 511;
  float4 ec = reinterpret_cast<const float4*>(Ec)[idx];
  float e00 = expf(ec.x), e01 = expf(ec.y), e10 = expf(ec.z), e11 = expf(ec.w);
  float s = e00 + e01 + e10 + e11;
  float inv = 1.f / s;
  e00 *= inv; e01 *= inv; e10 *= inv; e11 *= inv;
  float A0 = V[2*i], A1 = V[2*i+1];
  float B0 = V[2*j], B1 = V[2*j+1];
  for (int t = 0; t < 10; ++t) {
    float rm0 = e00 + e01 + EPSF, rm1 = e10 + e11 + EPSF;
    float cm0 = e00 + e10 + EPSF, cm1 = e01 + e11 + EPSF;
    float f0 = A0 / rm0, f1 = A1 / rm1;
    e00 *= f0; e01 *= f0; e10 *= f1; e11 *= f1;
    float g0 = B0 / cm0, g1 = B1 / cm1;
    e00 *= g0; e10 *= g0; e01 *= g1; e11 *= g1;
    float ss = e00 + e01 + e10 + e11 + EPSF;
    float iv = 1.f / ss;
    e00 *= iv; e01 *= iv; e10 *= iv; e11 *= iv;
  }
  if (i == j) { e00 = 0.f; e01 = 0.f; e10 = 0.f; e11 = 0.f; }
  e00 = fminf(fmaxf(e00, 0.f), 1.f);
  e01 = fminf(fmaxf(e01, 0.f), 1.f);
  e10 = fminf(fmaxf(e10, 0.f), 1.f);
  e11 = fminf(fmaxf(e11, 0.f), 1.f);
  reinterpret_cast<float2*>(E2)[idx]               = make_float2(e00, e01);  // plane xi=0
  reinterpret_cast<float2*>(E2 + PSTR)[idx]        = make_float2(e10, e11);  // plane xi=1
}

// ---------- Pr, invPr, sum(log Pr) per batch ----------
__global__ __launch_bounds__(256) void k_Pr(const int* __restrict__ x, const float* __restrict__ V,
                                            float* __restrict__ invPr, float* __restrict__ logPr) {
  const int b = blockIdx.x;
  const int tid = threadIdx.x;
  float acc = 0.f;
  for (int ii = tid; ii < NDIM; ii += 256) {
    const int xv = x[b*NDIM + ii];
    const float p = V[2*ii + xv];
    invPr[b*NDIM + ii] = 1.f / p;
    acc += logf(p);
  }
  for (int off = 32; off > 0; off >>= 1) acc += __shfl_down(acc, off, 64);
  __shared__ float sw[4];
  if ((tid & 63) == 0) sw[tid >> 6] = acc;
  __syncthreads();
  if (tid == 0) logPr[b] = sw[0] + sw[1] + sw[2] + sw[3];
}

// ---------- build full 512x512 embedded minors: row0 = e0, col0 = 0 ----------
// det(M) == det(Lb[1:,1:]); wave-per-row, 8 elems/lane, aligned float4 I/O, no barriers
__global__ __launch_bounds__(512) void k_build(const int* __restrict__ x, const float* __restrict__ E2,
                                               const float* __restrict__ Wm, const float* __restrict__ invPr,
                                               float* __restrict__ Mall) {
  const int b = blockIdx.x;                        // 0..128 (fast -> L2 reuse of Wm/E2 rows)
  const int i = blockIdx.y*8 + (threadIdx.x >> 6); // row 0..511, wave-uniform
  const int lane = threadIdx.x & 63;
  const int j0 = lane << 3;                        // 8 consecutive j per lane

  const float4 w0 = *(const float4*)(Wm + (size_t)i*NDIM + j0);
  const float4 w1 = *(const float4*)(Wm + (size_t)i*NDIM + j0 + 4);
  float wp[8];
  if (b < NB) {
    const int   xi   = x[b*NDIM + i];              // wave-uniform
    const float ipri = invPr[b*NDIM + i];          // wave-uniform
    const int4  xa = *(const int4*)(x + b*NDIM + j0);
    const int4  xb = *(const int4*)(x + b*NDIM + j0 + 4);
    const float4 pa = *(const float4*)(invPr + b*NDIM + j0);
    const float4 pb = *(const float4*)(invPr + b*NDIM + j0 + 4);
    // E2 pairs (xj=0,1) adjacent: one contiguous 64B chunk per lane
    const float* pl = E2 + (size_t)xi*PSTR + ((size_t)i*NDIM + j0)*2;
    const float4 ea = *(const float4*)(pl);
    const float4 eb = *(const float4*)(pl + 4);
    const float4 ec = *(const float4*)(pl + 8);
    const float4 ed = *(const float4*)(pl + 12);
    wp[0] = w0.x * (xa.x ? ea.y : ea.x) * pa.x;
    wp[1] = w0.y * (xa.y ? ea.w : ea.z) * pa.y;
    wp[2] = w0.z * (xa.z ? eb.y : eb.x) * pa.z;
    wp[3] = w0.w * (xa.w ? eb.w : eb.z) * pa.w;
    wp[4] = w1.x * (xb.x ? ec.y : ec.x) * pb.x;
    wp[5] = w1.y * (xb.y ? ec.w : ec.z) * pb.y;
    wp[6] = w1.z * (xb.z ? ed.y : ed.x) * pb.z;
    wp[7] = w1.w * (xb.w ? ed.w : ed.z) * pb.w;
    #pragma unroll
    for (int k = 0; k < 8; ++k) wp[k] *= ipri;
  } else {
    wp[0]=w0.x; wp[1]=w0.y; wp[2]=w0.z; wp[3]=w0.w;
    wp[4]=w1.x; wp[5]=w1.y; wp[6]=w1.z; wp[7]=w1.w;
  }
  // full row sum (includes j==0 term, matching reference diag) — in-wave butterfly
  float s = ((wp[0]+wp[1])+(wp[2]+wp[3])) + ((wp[4]+wp[5])+(wp[6]+wp[7]));
  #pragma unroll
  for (int off = 32; off > 0; off >>= 1) s += __shfl_xor(s, off, 64);

  float o[8];
  #pragma unroll
  for (int k = 0; k < 8; ++k) o[k] = -wp[k];
  if (i == 0) {
    #pragma unroll
    for (int k = 0; k < 8; ++k) o[k] = 0.f;
    if (lane == 0) o[0] = 1.f;                    // row 0 = e0
  } else {
    if (lane == 0) o[0] = 0.f;                    // col 0 = 0
    #pragma unroll
    for (int k = 0; k < 8; ++k)                   // static indices only (no scratch)
      if (j0 + k == i) o[k] = s;                  // diagonal = full row sum
  }
  float* dst = Mall + (size_t)b*MS + (size_t)i*NDIM + j0;
  *(float4*)(dst)   = make_float4(o[0],o[1],o[2],o[3]);
  *(float4*)(dst+4) = make_float4(o[4],o[5],o[6],o[7]);
}

// ---------- single-wave 64x64 LU of the diagonal block via readlane broadcast ----------
// lane r holds row r; same pivot order / arithmetic as the old barrier PanelStep.
template<int KK>
struct WFact {
  static __device__ __forceinline__ void run(float (&a)[64], const int lane,
                                             float& mypiv, float& myrec) {
    const float piv = rdlane(a[KK], KK);      // lane KK's a[KK]: wave-uniform SGPR
    const float rec = 1.0f / piv;
    if (lane == KK) { mypiv = piv; myrec = rec; }
    if (lane > KK) {
      const float l = a[KK] * rec;
      a[KK] = l;
      #pragma unroll
      for (int c = KK + 1; c < 64; ++c)
        a[c] -= l * rdlane(a[c], KK);         // readlane ignores EXEC: src lane value valid
    }
    WFact<KK + 1>::run(a, lane, mypiv, myrec);
  }
};
template<>
struct WFact<64> {
  static __device__ __forceinline__ void run(float (&)[64], int, float&, float&) {}
};

// ---------- L21 row triangular solve: a <- a * U11^{-1} (same op order as rank-1 form) ----------
template<int C>
struct SolveStep {
  static __device__ __forceinline__ void run(float (&a)[64], const float (*T)[72]) {
    float acc = a[C];
    #pragma unroll
    for (int p = 0; p < C; ++p)
      acc -= a[p] * T[C][p];                  // T[C][p] = U11[p][C], broadcast read
    a[C] = acc * T[C][66];                    // * 1/U11[C][C] (identical recip value)
    SolveStep<C + 1>::run(a, T);
  }
};
template<>
struct SolveStep<64> {
  static __device__ __forceinline__ void run(float (&)[64], const float (*)[72]) {}
};

// ---------- panel: wave0 factors diag block (no barriers), 1 syncthreads total ----------
// then: threads 64..m-1 solve L21 rows (barrier-free), threads 0..mrem-1 do U12 TRSM
__global__ __launch_bounds__(512) void k_panel(float* __restrict__ Mall, float* __restrict__ Lt,
                                               float* __restrict__ logdets, int k0, int mrem) {
  const int b = blockIdx.x;
  float* __restrict__ M = Mall + (size_t)b*MS;
  float* __restrict__ L = Lt + (size_t)b*LTS;
  const int t = threadIdx.x;
  const int m = NDIM - k0;          // 512,448,...,64
  __shared__ float T[64][72];       // T[c][r] = factored_block[r][c]; recip diag at T[c][66]

  float a[64];
  if (t < m) {
    const float* row = M + (size_t)(k0+t)*NDIM + k0;
    #pragma unroll
    for (int c4 = 0; c4 < 16; ++c4) {
      float4 v = *(const float4*)(row + c4*4);
      a[c4*4+0]=v.x; a[c4*4+1]=v.y; a[c4*4+2]=v.z; a[c4*4+3]=v.w;
    }
  }

  if (t < 64) {
    float mypiv = 1.f, myrec = 1.f;
    WFact<0>::run(a, t, mypiv, myrec);
    // publish transposed factored block + recip diag
    #pragma unroll
    for (int c = 0; c < 64; ++c) T[c][t] = a[c];
    T[t][66] = myrec;
    // logdet contribution: lane t saw pivot t
    float v = logf(fabsf(mypiv));
    #pragma unroll
    for (int off = 32; off > 0; off >>= 1) v += __shfl_down(v, off, 64);
    if (t == 0) logdets[b] = (k0 == 0) ? v : (logdets[b] + v);
  }
  __syncthreads();

  if (mrem > 0) {
    // ---- L21 rows: barrier-free triangular solve, then write transposed panel ----
    if (t >= 64 && t < m) {
      SolveStep<0>::run(a, T);
      #pragma unroll
      for (int c = 0; c < 64; ++c) L[(size_t)c*NDIM + t] = a[c];   // Lt[c][r], coalesced
    }
    // ---- TRSM: U12 = L11^{-1} A12, one column per thread (mrem <= 448 < 512) ----
    if (t < mrem) {
      const int col = k0 + 64 + t;
      float u[64];
      #pragma unroll
      for (int r = 0; r < 64; ++r) u[r] = M[(size_t)(k0+r)*NDIM + col];
      #pragma unroll
      for (int p = 0; p < 63; ++p) {
        const float lv = u[p];
        #pragma unroll
        for (int kk = p+1; kk < 64; ++kk)
          u[kk] -= T[p][kk] * lv;             // T[p][kk] = L11[kk][p]
      }
      #pragma unroll
      for (int r = 1; r < 64; ++r) M[(size_t)(k0+r)*NDIM + col] = u[r];
    }
  }
}

// ---------- trailing update: C -= L21 * U12, 64x64 tile, 4x4/thread ----------
__global__ __launch_bounds__(256, 4) void k_gemm(float* __restrict__ Mall, const float* __restrict__ Lt,
                                                 int k0) {
  const int b = blockIdx.x;
  float* __restrict__ M = Mall + (size_t)b*MS;
  const float* __restrict__ L = Lt + (size_t)b*LTS;
  __shared__ float As[64][68];     // As[p][r] = L21[r][p]
  __shared__ float Bs[64][68];     // Bs[p][c] = U12[p][c]
  const int tid = threadIdx.x;
  const int tx = tid & 15, ty = tid >> 4;
  const int rowbase = 64 + blockIdx.y*64;   // panel-local row of C tile
  const int colbase = 64 + blockIdx.z*64;   // panel-local col
  #pragma unroll
  for (int i = 0; i < 4; ++i) {
    int q = tid + 256*i;           // 1024 float4
    int p = q >> 4, f = q & 15;
    *(float4*)&As[p][f*4] = *(const float4*)&L[(size_t)p*NDIM + rowbase + f*4];
    *(float4*)&Bs[p][f*4] = *(const float4*)&M[(size_t)(k0+p)*NDIM + (k0+colbase) + f*4];
  }
  float* Crow = M + (size_t)(k0+rowbase+ty*4)*NDIM + (k0+colbase+tx*4);
  float4 c0 = *(float4*)(Crow + 0*NDIM);
  float4 c1 = *(float4*)(Crow + 1*NDIM);
  float4 c2 = *(float4*)(Crow + 2*NDIM);
  float4 c3 = *(float4*)(Crow + 3*NDIM);
  __syncthreads();
  #pragma unroll
  for (int p = 0; p < 64; ++p) {
    const float4 av = *(const float4*)&As[p][ty*4];
    const float4 bv = *(const float4*)&Bs[p][tx*4];
    c0.x -= av.x*bv.x; c0.y -= av.x*bv.y; c0.z -= av.x*bv.z; c0.w -= av.x*bv.w;
    c1.x -= av.y*bv.x; c1.y -= av.y*bv.y; c1.z -= av.y*bv.z; c1.w -= av.y*bv.w;
    c2.x -= av.z*bv.x; c2.y -= av.z*bv.y; c2.z -= av.z*bv.z; c2.w -= av.z*bv.w;
    c3.x -= av.w*bv.x; c3.y -= av.w*bv.y; c3.z -= av.w*bv.z; c3.w -= av.w*bv.w;
  }
  *(float4*)(Crow + 0*NDIM) = c0;
  *(float4*)(Crow + 1*NDIM) = c1;
  *(float4*)(Crow + 2*NDIM) = c2;
  *(float4*)(Crow + 3*NDIM) = c3;
}

// ---------- final combine ----------
__global__ void k_final(const float* __restrict__ logPr, const float* __restrict__ logdets,
                        float* __restrict__ out) {
  int t = threadIdx.x;
  if (t < NB) out[t] = logPr[t] + logdets[t] - logdets[NB];
}

extern "C" void kernel_launch(void* const* d_in, const int* in_sizes, int n_in,
                              void* d_out, int out_size, void* d_ws, size_t ws_size,
                              hipStream_t stream) {
  const int*   x  = (const int*)  d_in[0];
  const float* W  = (const float*)d_in[1];
  const float* Vc = (const float*)d_in[2];
  const float* Ec = (const float*)d_in[3];
  float* out = (float*)d_out;
  float* ws  = (float*)d_ws;
  (void)in_sizes; (void)n_in; (void)out_size; (void)ws_size;  // needs ~158 MiB of ws

  float* Mat = ws + OFF_MAT;
  float* Lt  = ws + OFF_LT;
  float* Ld  = ws + OFF_LD;

  k_V  <<<2,    256, 0, stream>>>(Vc, ws + OFF_V);
  k_Wm <<<1024, 256, 0, stream>>>(W,  ws + OFF_WM);
  k_E  <<<1024, 256, 0, stream>>>(Ec, ws + OFF_V, ws + OFF_E);
  k_Pr <<<NB,   256, 0, stream>>>(x,  ws + OFF_V, ws + OFF_IPR, ws + OFF_LPR);
  dim3 gb(NMAT, 64);
  k_build<<<gb, 512, 0, stream>>>(x, ws + OFF_E, ws + OFF_WM, ws + OFF_IPR, Mat);

  for (int s = 0; s < 8; ++s) {
    const int k0 = s*64;
    const int mrem = NDIM - k0 - 64;
    k_panel<<<NMAT, 512, 0, stream>>>(Mat, Lt, Ld, k0, mrem);
    if (mrem > 0) {
      const int nt = mrem/64;
      dim3 gg(NMAT, nt, nt);
      k_gemm<<<gg, 256, 0, stream>>>(Mat, Lt, k0);
    }
  }
  k_final<<<1, 128, 0, stream>>>(ws + OFF_LPR, Ld, out);
}